// Round 1
// baseline (1359.593 us; speedup 1.0000x reference)
//
#include <hip/hip_runtime.h>
#include <hip/hip_bf16.h>

typedef __bf16 bf16_t;
typedef bf16_t bf16x8 __attribute__((ext_vector_type(8)));
typedef float f32x4 __attribute__((ext_vector_type(4)));

#define LD 104  // padded LDS row stride in bf16 elems (96 + 8)

// ---------------- weight convert: 5 x [96][96] f32 -> bf16 ----------------
__global__ void conv_w_kernel(const float* __restrict__ A, const float* __restrict__ B,
                              const float* __restrict__ C, const float* __restrict__ Dw,
                              const float* __restrict__ Ew, bf16_t* __restrict__ wb) {
    int i = blockIdx.x * 256 + threadIdx.x;
    if (i >= 5 * 9216) return;
    int m = i / 9216, j = i % 9216;
    const float* p = (m == 0) ? A : (m == 1) ? B : (m == 2) ? C : (m == 3) ? Dw : Ew;
    wb[i] = (bf16_t)p[j];
}

// ---------------- node GEMM: nodeF[n][mat*96+c] = (h @ W^T + b) ----------------
// mat 0..3 -> A,B,Dl,El  (wb idx 0,1,3,4)
__global__ __launch_bounds__(256) void node_gemm_kernel(
    const float* __restrict__ h, const bf16_t* __restrict__ wb,
    const float* __restrict__ Ab, const float* __restrict__ Bb,
    const float* __restrict__ Db, const float* __restrict__ Eb,
    float* __restrict__ nodeF, int N)
{
    __shared__ __align__(16) bf16_t sx[64 * LD];
    __shared__ __align__(16) bf16_t sw[96 * LD];
    const int mat = blockIdx.y;
    const int widx = (mat < 2) ? mat : mat + 1;
    const float* bias = (mat == 0) ? Ab : (mat == 1) ? Bb : (mat == 2) ? Db : Eb;
    const int n0 = blockIdx.x * 64;
    const int t = threadIdx.x;

    for (int i = t; i < 64 * 96; i += 256) {
        int r = i / 96, c = i % 96;
        int n = n0 + r;
        float v = (n < N) ? h[n * 96 + c] : 0.f;
        sx[r * LD + c] = (bf16_t)v;
    }
    {
        const unsigned* W4 = (const unsigned*)(wb + widx * 9216);
        for (int i = t; i < 96 * 48; i += 256) {
            int r = i / 48, c = (i % 48) * 2;
            *(unsigned*)&sw[r * LD + c] = W4[i];
        }
    }
    __syncthreads();

    const int w = t >> 6, l = t & 63;
    const int lr = l & 15, lkb = (l >> 4) * 8;
    f32x4 acc[6];
#pragma unroll
    for (int i = 0; i < 6; ++i) acc[i] = (f32x4){0.f, 0.f, 0.f, 0.f};
    const bf16_t* aP = &sx[(w * 16 + lr) * LD + lkb];
#pragma unroll
    for (int kk = 0; kk < 3; ++kk) {
        bf16x8 a = *(const bf16x8*)(aP + kk * 32);
#pragma unroll
        for (int tn = 0; tn < 6; ++tn) {
            bf16x8 b = *(const bf16x8*)(&sw[(tn * 16 + lr) * LD + kk * 32 + lkb]);
            acc[tn] = __builtin_amdgcn_mfma_f32_16x16x32_bf16(a, b, acc[tn], 0, 0, 0);
        }
    }
    const int rowb = (l >> 4) * 4;
#pragma unroll
    for (int tn = 0; tn < 6; ++tn) {
        const int col = tn * 16 + lr;
        const float bv = bias[col];
#pragma unroll
        for (int i = 0; i < 4; ++i) {
            int n = n0 + w * 16 + rowb + i;
            if (n < N) nodeF[n * 384 + mat * 96 + col] = acc[tn][i] + bv;
        }
    }
}

// ---------------- edge passes ----------------
// PASS==1: e_new = Ce + Dh[src] + Eh[dst]; sigma; atomic scatter; BN-e stats
// PASS==0: recompute e_new; e_out = e + relu(e_new*sc_e + sh_e)
template <int PASS>
__global__ __launch_bounds__(256) void edge_kernel(
    const float* __restrict__ eP, const int* __restrict__ src, const int* __restrict__ dst,
    const bf16_t* __restrict__ wb, const float* __restrict__ Cb,
    const float* __restrict__ nodeF, float* __restrict__ node_acc,
    float* __restrict__ stats, const float* __restrict__ coef,
    float* __restrict__ eout, int E)
{
    __shared__ __align__(16) bf16_t se[64 * LD];
    __shared__ __align__(16) bf16_t sw[96 * LD];
    __shared__ int ssrc[64], sdst[64];
    __shared__ float bns[96], bnq[96];
    const int t = threadIdx.x;
    const int e0 = blockIdx.x * 64;

    {
        const unsigned* W4 = (const unsigned*)(wb + 2 * 9216);  // C_w
        for (int i = t; i < 96 * 48; i += 256) {
            int r = i / 48, c = (i % 48) * 2;
            *(unsigned*)&sw[r * LD + c] = W4[i];
        }
    }
    for (int i = t; i < 64 * 96; i += 256) {
        int r = i / 96, c = i % 96;
        int ge = e0 + r;
        float v = (ge < E) ? eP[ge * 96 + c] : 0.f;
        se[r * LD + c] = (bf16_t)v;
    }
    if (t < 64) {
        int ge = e0 + t;
        ssrc[t] = (ge < E) ? src[ge] : 0;
        sdst[t] = (ge < E) ? dst[ge] : 0;
    }
    if (PASS == 1 && t < 96) { bns[t] = 0.f; bnq[t] = 0.f; }
    __syncthreads();

    const int w = t >> 6, l = t & 63;
    const int lr = l & 15, lkb = (l >> 4) * 8;
    f32x4 acc[6];
#pragma unroll
    for (int i = 0; i < 6; ++i) acc[i] = (f32x4){0.f, 0.f, 0.f, 0.f};
    const bf16_t* aP = &se[(w * 16 + lr) * LD + lkb];
#pragma unroll
    for (int kk = 0; kk < 3; ++kk) {
        bf16x8 a = *(const bf16x8*)(aP + kk * 32);
#pragma unroll
        for (int tn = 0; tn < 6; ++tn) {
            bf16x8 b = *(const bf16x8*)(&sw[(tn * 16 + lr) * LD + kk * 32 + lkb]);
            acc[tn] = __builtin_amdgcn_mfma_f32_16x16x32_bf16(a, b, acc[tn], 0, 0, 0);
        }
    }

    const int rowb = (l >> 4) * 4;
#pragma unroll
    for (int tn = 0; tn < 6; ++tn) {
        const int col = tn * 16 + lr;
        const float cbv = Cb[col];
        float sc_e = 0.f, sh_e = 0.f;
        if (PASS == 0) { sc_e = coef[192 + col]; sh_e = coef[288 + col]; }
        float ls = 0.f, lq = 0.f;
#pragma unroll
        for (int i = 0; i < 4; ++i) {
            const int r = w * 16 + rowb + i;
            const int ge = e0 + r;
            if (ge < E) {
                const int s = ssrc[r], dd = sdst[r];
                float en = acc[tn][i] + cbv + nodeF[s * 384 + 192 + col] + nodeF[dd * 384 + 288 + col];
                if (PASS == 1) {
                    float sg = 1.f / (1.f + __expf(-en));
                    unsafeAtomicAdd(&node_acc[dd * 192 + col], sg * nodeF[s * 384 + 96 + col]);
                    unsafeAtomicAdd(&node_acc[dd * 192 + 96 + col], sg);
                    ls += en; lq += en * en;
                } else {
                    float res = eP[ge * 96 + col];
                    eout[ge * 96 + col] = res + fmaxf(0.f, en * sc_e + sh_e);
                }
            }
        }
        if (PASS == 1) { atomicAdd(&bns[col], ls); atomicAdd(&bnq[col], lq); }
    }
    if (PASS == 1) {
        __syncthreads();
        if (t < 96) {
            unsafeAtomicAdd(&stats[192 + t], bns[t]);
            unsafeAtomicAdd(&stats[288 + t], bnq[t]);
        }
    }
}

// ---------------- h_new + BN-h stats ----------------
__global__ __launch_bounds__(192) void h_new_kernel(
    const float* __restrict__ nodeF, const float* __restrict__ node_acc,
    float* __restrict__ h_new, float* __restrict__ stats, int N)
{
    __shared__ float bs[192], bq[192];
    const int t = threadIdx.x;
    const int col = t % 96, half = t / 96;
    const int n0 = blockIdx.x * 32;
    float ls = 0.f, lq = 0.f;
    for (int r = half; r < 32; r += 2) {
        int n = n0 + r;
        if (n >= N) break;
        float ssum = node_acc[n * 192 + 96 + col];
        float shh = node_acc[n * 192 + col];
        float v = nodeF[n * 384 + col] + shh / (ssum + 1e-6f);
        h_new[n * 96 + col] = v;
        ls += v; lq += v * v;
    }
    bs[t] = ls; bq[t] = lq;
    __syncthreads();
    if (t < 96) {
        unsafeAtomicAdd(&stats[t], bs[t] + bs[t + 96]);
        unsafeAtomicAdd(&stats[96 + t], bq[t] + bq[t + 96]);
    }
}

// ---------------- stats -> scale/shift coefs ----------------
__global__ void finalize_stats_kernel(const float* __restrict__ stats, float* __restrict__ coef,
                                      const float* __restrict__ gh, const float* __restrict__ bh,
                                      const float* __restrict__ ge, const float* __restrict__ be,
                                      int N, int E)
{
    int t = threadIdx.x;
    if (t < 96) {
        float m = stats[t] / (float)N;
        float v = stats[96 + t] / (float)N - m * m;
        float rs = rsqrtf(v + 1e-5f);
        float sc = gh[t] * rs;
        coef[t] = sc;
        coef[96 + t] = bh[t] - m * sc;
    } else if (t < 192) {
        int c = t - 96;
        float m = stats[192 + c] / (float)E;
        float v = stats[288 + c] / (float)E - m * m;
        float rs = rsqrtf(v + 1e-5f);
        float sc = ge[c] * rs;
        coef[192 + c] = sc;
        coef[288 + c] = be[c] - m * sc;
    }
}

// ---------------- h output: h + relu(h_new*sc + sh) ----------------
__global__ __launch_bounds__(256) void h_out_kernel(
    const float* __restrict__ h, const float* __restrict__ h_new,
    const float* __restrict__ coef, float* __restrict__ out, int N)
{
    int idx = blockIdx.x * 256 + threadIdx.x;  // one float4
    int total = N * 24;
    if (idx >= total) return;
    int c4 = (idx % 24) * 4;
    float4 hv = ((const float4*)h)[idx];
    float4 nv = ((const float4*)h_new)[idx];
    float4 o;
    o.x = hv.x + fmaxf(0.f, nv.x * coef[c4 + 0] + coef[96 + c4 + 0]);
    o.y = hv.y + fmaxf(0.f, nv.y * coef[c4 + 1] + coef[96 + c4 + 1]);
    o.z = hv.z + fmaxf(0.f, nv.z * coef[c4 + 2] + coef[96 + c4 + 2]);
    o.w = hv.w + fmaxf(0.f, nv.w * coef[c4 + 3] + coef[96 + c4 + 3]);
    ((float4*)out)[idx] = o;
}

extern "C" void kernel_launch(void* const* d_in, const int* in_sizes, int n_in,
                              void* d_out, int out_size, void* d_ws, size_t ws_size,
                              hipStream_t stream)
{
    const float* h   = (const float*)d_in[0];
    const float* e   = (const float*)d_in[1];
    const int*   src = (const int*)d_in[2];
    const int*   dst = (const int*)d_in[3];
    const float* Aw  = (const float*)d_in[4];
    const float* Ab  = (const float*)d_in[5];
    const float* Bw  = (const float*)d_in[6];
    const float* Bb  = (const float*)d_in[7];
    const float* Cw  = (const float*)d_in[8];
    const float* Cb  = (const float*)d_in[9];
    const float* Dw  = (const float*)d_in[10];
    const float* Db  = (const float*)d_in[11];
    const float* Ewt = (const float*)d_in[12];
    const float* Eb  = (const float*)d_in[13];
    const float* gh  = (const float*)d_in[14];
    const float* bh  = (const float*)d_in[15];
    const float* ge  = (const float*)d_in[16];
    const float* be  = (const float*)d_in[17];

    const int N = in_sizes[0] / 96;
    const int E = in_sizes[2];

    float* ws       = (float*)d_ws;
    float* nodeF    = ws;                               // N*384
    float* node_acc = nodeF + (size_t)N * 384;          // N*192
    float* h_new    = node_acc + (size_t)N * 192;       // N*96
    float* stats    = h_new + (size_t)N * 96;           // 384
    float* coef     = stats + 384;                      // 384
    bf16_t* wb      = (bf16_t*)(coef + 384);            // 5*9216 bf16

    hipMemsetAsync(node_acc, 0, (size_t)N * 192 * sizeof(float), stream);
    hipMemsetAsync(stats, 0, 384 * sizeof(float), stream);

    conv_w_kernel<<<dim3(180), dim3(256), 0, stream>>>(Aw, Bw, Cw, Dw, Ewt, wb);
    node_gemm_kernel<<<dim3((N + 63) / 64, 4), dim3(256), 0, stream>>>(h, wb, Ab, Bb, Db, Eb, nodeF, N);
    edge_kernel<1><<<dim3((E + 63) / 64), dim3(256), 0, stream>>>(
        e, src, dst, wb, Cb, nodeF, node_acc, stats, nullptr, nullptr, E);
    h_new_kernel<<<dim3((N + 31) / 32), dim3(192), 0, stream>>>(nodeF, node_acc, h_new, stats, N);
    finalize_stats_kernel<<<dim3(1), dim3(192), 0, stream>>>(stats, coef, gh, bh, ge, be, N, E);
    h_out_kernel<<<dim3((N * 24 + 255) / 256), dim3(256), 0, stream>>>(h, h_new, coef, (float*)d_out, N);
    edge_kernel<0><<<dim3((E + 63) / 64), dim3(256), 0, stream>>>(
        e, src, dst, wb, Cb, nodeF, nullptr, nullptr, coef, (float*)d_out + (size_t)N * 96, E);
}

// Round 2
// 1195.249 us; speedup vs baseline: 1.1375x; 1.1375x over previous
//
#include <hip/hip_runtime.h>
#include <hip/hip_bf16.h>

typedef __bf16 bf16_t;
typedef bf16_t bf16x8 __attribute__((ext_vector_type(8)));
typedef float f32x4 __attribute__((ext_vector_type(4)));

#define LD 104  // padded LDS row stride in bf16 elems (96 + 8)
#define PVLD 194 // padded f32 stride for the 64x192 p-value tile (2-way banks = free)

// ---------------- weight convert: 5 x [96][96] f32 -> bf16 ----------------
__global__ void conv_w_kernel(const float* __restrict__ A, const float* __restrict__ B,
                              const float* __restrict__ C, const float* __restrict__ Dw,
                              const float* __restrict__ Ew, bf16_t* __restrict__ wb) {
    int i = blockIdx.x * 256 + threadIdx.x;
    if (i >= 5 * 9216) return;
    int m = i / 9216, j = i % 9216;
    const float* p = (m == 0) ? A : (m == 1) ? B : (m == 2) ? C : (m == 3) ? Dw : Ew;
    wb[i] = (bf16_t)p[j];
}

// ---------------- node GEMM: nodeF[n][mat*96+c] = (h @ W^T + b) ----------------
__global__ __launch_bounds__(256) void node_gemm_kernel(
    const float* __restrict__ h, const bf16_t* __restrict__ wb,
    const float* __restrict__ Ab, const float* __restrict__ Bb,
    const float* __restrict__ Db, const float* __restrict__ Eb,
    float* __restrict__ nodeF, int N)
{
    __shared__ __align__(16) bf16_t sx[64 * LD];
    __shared__ __align__(16) bf16_t sw[96 * LD];
    const int mat = blockIdx.y;
    const int widx = (mat < 2) ? mat : mat + 1;
    const float* bias = (mat == 0) ? Ab : (mat == 1) ? Bb : (mat == 2) ? Db : Eb;
    const int n0 = blockIdx.x * 64;
    const int t = threadIdx.x;

    for (int i = t; i < 64 * 96; i += 256) {
        int r = i / 96, c = i % 96;
        int n = n0 + r;
        float v = (n < N) ? h[n * 96 + c] : 0.f;
        sx[r * LD + c] = (bf16_t)v;
    }
    {
        const unsigned* W4 = (const unsigned*)(wb + widx * 9216);
        for (int i = t; i < 96 * 48; i += 256) {
            int r = i / 48, c = (i % 48) * 2;
            *(unsigned*)&sw[r * LD + c] = W4[i];
        }
    }
    __syncthreads();

    const int w = t >> 6, l = t & 63;
    const int lr = l & 15, lkb = (l >> 4) * 8;
    f32x4 acc[6];
#pragma unroll
    for (int i = 0; i < 6; ++i) acc[i] = (f32x4){0.f, 0.f, 0.f, 0.f};
    const bf16_t* aP = &sx[(w * 16 + lr) * LD + lkb];
#pragma unroll
    for (int kk = 0; kk < 3; ++kk) {
        bf16x8 a = *(const bf16x8*)(aP + kk * 32);
#pragma unroll
        for (int tn = 0; tn < 6; ++tn) {
            bf16x8 b = *(const bf16x8*)(&sw[(tn * 16 + lr) * LD + kk * 32 + lkb]);
            acc[tn] = __builtin_amdgcn_mfma_f32_16x16x32_bf16(a, b, acc[tn], 0, 0, 0);
        }
    }
    const int rowb = (l >> 4) * 4;
#pragma unroll
    for (int tn = 0; tn < 6; ++tn) {
        const int col = tn * 16 + lr;
        const float bv = bias[col];
#pragma unroll
        for (int i = 0; i < 4; ++i) {
            int n = n0 + w * 16 + rowb + i;
            if (n < N) nodeF[n * 384 + mat * 96 + col] = acc[tn][i] + bv;
        }
    }
}

// ---------------- counting sort by dst ----------------
__global__ void hist_kernel(const int* __restrict__ dst, int* __restrict__ cnt, int E) {
    int i = blockIdx.x * 256 + threadIdx.x;
    if (i < E) atomicAdd(&cnt[dst[i]], 1);
}

__global__ __launch_bounds__(1024) void scan_kernel(const int* __restrict__ cnt,
                                                    int* __restrict__ rowptr, int N) {
    __shared__ int wsum[16];
    __shared__ int s_carry;
    const int t = threadIdx.x;
    const int w = t >> 6, l = t & 63;
    if (t == 0) s_carry = 0;
    __syncthreads();
    for (int base = 0; base < N; base += 1024) {
        int v = (base + t < N) ? cnt[base + t] : 0;
        int x = v;
#pragma unroll
        for (int d = 1; d < 64; d <<= 1) {
            int y = __shfl_up(x, d, 64);
            if (l >= d) x += y;
        }
        if (l == 63) wsum[w] = x;
        __syncthreads();
        int carry = s_carry;
        int woff = 0;
        for (int i = 0; i < w; ++i) woff += wsum[i];
        int incl = carry + woff + x;
        if (base + t < N) rowptr[base + t] = incl - v;
        __syncthreads();
        if (t == 1023) s_carry = incl;
    }
}

__global__ void scatter_kernel(const int* __restrict__ dst, int* __restrict__ cursor,
                               int* __restrict__ perm, int E) {
    int i = blockIdx.x * 256 + threadIdx.x;
    if (i < E) {
        int p = atomicAdd(&cursor[dst[i]], 1);
        perm[p] = i;
    }
}

// ---------------- edge aggregation over dst-sorted edges ----------------
// computes e_new = Ce + Dh[src] + Eh[dst], sigma; BN-e stats; segmented
// reduction of [sigma*Bh[src], sigma] into node_acc (few atomics per block).
__global__ __launch_bounds__(256) void edge_agg_kernel(
    const float* __restrict__ eP, const int* __restrict__ src, const int* __restrict__ dst,
    const int* __restrict__ perm,
    const bf16_t* __restrict__ wb, const float* __restrict__ Cb,
    const float* __restrict__ nodeF, float* __restrict__ node_acc,
    float* __restrict__ stats, int E)
{
    __shared__ __align__(16) char smem[64 * PVLD * 4];  // 49664 B, staging overlaps pv
    bf16_t* se = (bf16_t*)smem;                    // [64][LD]
    bf16_t* sw = (bf16_t*)(smem + 64 * LD * 2);    // [96][LD]
    float*  pv = (float*)smem;                     // [64][PVLD]
    __shared__ int seid[64], ssrc[64], sdst[64];
    __shared__ float bns[96], bnq[96];

    const int t = threadIdx.x;
    const int e0 = blockIdx.x * 64;

    if (t < 64) {
        int ge = e0 + t;
        int eid = (ge < E) ? perm[ge] : -1;
        seid[t] = eid;
        ssrc[t] = (eid >= 0) ? src[eid] : 0;
        sdst[t] = (eid >= 0) ? dst[eid] : 0;
    }
    if (t >= 64 && t < 160) { bns[t - 64] = 0.f; bnq[t - 64] = 0.f; }
    __syncthreads();

    {
        const unsigned* W4 = (const unsigned*)(wb + 2 * 9216);  // C_w
        for (int i = t; i < 96 * 48; i += 256) {
            int r = i / 48, c = (i % 48) * 2;
            *(unsigned*)&sw[r * LD + c] = W4[i];
        }
    }
    for (int i = t; i < 64 * 24; i += 256) {
        int r = i / 24, c4 = i % 24;
        int eid = seid[r];
        float4 v = (eid >= 0) ? ((const float4*)eP)[(size_t)eid * 24 + c4]
                              : make_float4(0.f, 0.f, 0.f, 0.f);
        bf16_t* p = &se[r * LD + c4 * 4];
        p[0] = (bf16_t)v.x; p[1] = (bf16_t)v.y; p[2] = (bf16_t)v.z; p[3] = (bf16_t)v.w;
    }
    __syncthreads();

    const int w = t >> 6, l = t & 63;
    const int lr = l & 15, lkb = (l >> 4) * 8;
    f32x4 acc[6];
#pragma unroll
    for (int i = 0; i < 6; ++i) acc[i] = (f32x4){0.f, 0.f, 0.f, 0.f};
    const bf16_t* aP = &se[(w * 16 + lr) * LD + lkb];
#pragma unroll
    for (int kk = 0; kk < 3; ++kk) {
        bf16x8 a = *(const bf16x8*)(aP + kk * 32);
#pragma unroll
        for (int tn = 0; tn < 6; ++tn) {
            bf16x8 b = *(const bf16x8*)(&sw[(tn * 16 + lr) * LD + kk * 32 + lkb]);
            acc[tn] = __builtin_amdgcn_mfma_f32_16x16x32_bf16(a, b, acc[tn], 0, 0, 0);
        }
    }

    __syncthreads();  // all LDS (se/sw) reads done; pv may now overwrite them

    const int rowb = (l >> 4) * 4;
    float lss[6] = {0, 0, 0, 0, 0, 0}, lqq[6] = {0, 0, 0, 0, 0, 0};
#pragma unroll
    for (int i = 0; i < 4; ++i) {
        const int r = w * 16 + rowb + i;
        const bool ok = (seid[r] >= 0);
        const int s = ssrc[r], dd = sdst[r];
#pragma unroll
        for (int tn = 0; tn < 6; ++tn) {
            const int col = tn * 16 + lr;
            float sg = 0.f, sh = 0.f;
            if (ok) {
                float en = acc[tn][i] + Cb[col] + nodeF[s * 384 + 192 + col]
                         + nodeF[dd * 384 + 288 + col];
                sg = 1.f / (1.f + __expf(-en));
                sh = sg * nodeF[s * 384 + 96 + col];
                lss[tn] += en; lqq[tn] += en * en;
            }
            pv[r * PVLD + col] = sh;
            pv[r * PVLD + 96 + col] = sg;
        }
    }

    // BN-e stats: fold the 4 row-groups (lanes differing in bits 4,5 share col)
#pragma unroll
    for (int tn = 0; tn < 6; ++tn) {
        float ls = lss[tn], lq = lqq[tn];
        ls += __shfl_xor(ls, 16, 64); lq += __shfl_xor(lq, 16, 64);
        ls += __shfl_xor(ls, 32, 64); lq += __shfl_xor(lq, 32, 64);
        if (l < 16) {
            atomicAdd(&bns[tn * 16 + lr], ls);
            atomicAdd(&bnq[tn * 16 + lr], lq);
        }
    }
    __syncthreads();  // pv complete + bns/bnq complete

    if (t < 192) {
        float run = 0.f;
        int prev = sdst[0];
        for (int r = 0; r < 64; ++r) {
            int d = sdst[r];
            if (d != prev) {
                unsafeAtomicAdd(&node_acc[(size_t)prev * 192 + t], run);
                run = 0.f;
                prev = d;
            }
            run += pv[r * PVLD + t];
        }
        unsafeAtomicAdd(&node_acc[(size_t)prev * 192 + t], run);
    }
    if (t < 96) {
        unsafeAtomicAdd(&stats[192 + t], bns[t]);
        unsafeAtomicAdd(&stats[288 + t], bnq[t]);
    }
}

// ---------------- edge output pass: e_out = e + relu(BN(e_new)) ----------------
__global__ __launch_bounds__(256) void edge_out_kernel(
    const float* __restrict__ eP, const int* __restrict__ src, const int* __restrict__ dst,
    const bf16_t* __restrict__ wb, const float* __restrict__ Cb,
    const float* __restrict__ nodeF, const float* __restrict__ coef,
    float* __restrict__ eout, int E)
{
    __shared__ __align__(16) bf16_t se[64 * LD];
    __shared__ __align__(16) bf16_t sw[96 * LD];
    __shared__ int ssrc[64], sdst[64];
    const int t = threadIdx.x;
    const int e0 = blockIdx.x * 64;

    {
        const unsigned* W4 = (const unsigned*)(wb + 2 * 9216);  // C_w
        for (int i = t; i < 96 * 48; i += 256) {
            int r = i / 48, c = (i % 48) * 2;
            *(unsigned*)&sw[r * LD + c] = W4[i];
        }
    }
    for (int i = t; i < 64 * 96; i += 256) {
        int r = i / 96, c = i % 96;
        int ge = e0 + r;
        float v = (ge < E) ? eP[ge * 96 + c] : 0.f;
        se[r * LD + c] = (bf16_t)v;
    }
    if (t < 64) {
        int ge = e0 + t;
        ssrc[t] = (ge < E) ? src[ge] : 0;
        sdst[t] = (ge < E) ? dst[ge] : 0;
    }
    __syncthreads();

    const int w = t >> 6, l = t & 63;
    const int lr = l & 15, lkb = (l >> 4) * 8;
    f32x4 acc[6];
#pragma unroll
    for (int i = 0; i < 6; ++i) acc[i] = (f32x4){0.f, 0.f, 0.f, 0.f};
    const bf16_t* aP = &se[(w * 16 + lr) * LD + lkb];
#pragma unroll
    for (int kk = 0; kk < 3; ++kk) {
        bf16x8 a = *(const bf16x8*)(aP + kk * 32);
#pragma unroll
        for (int tn = 0; tn < 6; ++tn) {
            bf16x8 b = *(const bf16x8*)(&sw[(tn * 16 + lr) * LD + kk * 32 + lkb]);
            acc[tn] = __builtin_amdgcn_mfma_f32_16x16x32_bf16(a, b, acc[tn], 0, 0, 0);
        }
    }

    const int rowb = (l >> 4) * 4;
#pragma unroll
    for (int tn = 0; tn < 6; ++tn) {
        const int col = tn * 16 + lr;
        const float cbv = Cb[col];
        const float sc_e = coef[192 + col];
        const float sh_e = coef[288 + col];
#pragma unroll
        for (int i = 0; i < 4; ++i) {
            const int r = w * 16 + rowb + i;
            const int ge = e0 + r;
            if (ge < E) {
                const int s = ssrc[r], dd = sdst[r];
                float en = acc[tn][i] + cbv + nodeF[s * 384 + 192 + col]
                         + nodeF[dd * 384 + 288 + col];
                float res = eP[ge * 96 + col];
                eout[ge * 96 + col] = res + fmaxf(0.f, en * sc_e + sh_e);
            }
        }
    }
}

// ---------------- h_new + BN-h stats ----------------
__global__ __launch_bounds__(192) void h_new_kernel(
    const float* __restrict__ nodeF, const float* __restrict__ node_acc,
    float* __restrict__ h_new, float* __restrict__ stats, int N)
{
    __shared__ float bs[192], bq[192];
    const int t = threadIdx.x;
    const int col = t % 96, half = t / 96;
    const int n0 = blockIdx.x * 32;
    float ls = 0.f, lq = 0.f;
    for (int r = half; r < 32; r += 2) {
        int n = n0 + r;
        if (n >= N) break;
        float ssum = node_acc[n * 192 + 96 + col];
        float shh = node_acc[n * 192 + col];
        float v = nodeF[n * 384 + col] + shh / (ssum + 1e-6f);
        h_new[n * 96 + col] = v;
        ls += v; lq += v * v;
    }
    bs[t] = ls; bq[t] = lq;
    __syncthreads();
    if (t < 96) {
        unsafeAtomicAdd(&stats[t], bs[t] + bs[t + 96]);
        unsafeAtomicAdd(&stats[96 + t], bq[t] + bq[t + 96]);
    }
}

// ---------------- stats -> scale/shift coefs ----------------
__global__ void finalize_stats_kernel(const float* __restrict__ stats, float* __restrict__ coef,
                                      const float* __restrict__ gh, const float* __restrict__ bh,
                                      const float* __restrict__ ge, const float* __restrict__ be,
                                      int N, int E)
{
    int t = threadIdx.x;
    if (t < 96) {
        float m = stats[t] / (float)N;
        float v = stats[96 + t] / (float)N - m * m;
        float rs = rsqrtf(v + 1e-5f);
        float sc = gh[t] * rs;
        coef[t] = sc;
        coef[96 + t] = bh[t] - m * sc;
    } else if (t < 192) {
        int c = t - 96;
        float m = stats[192 + c] / (float)E;
        float v = stats[288 + c] / (float)E - m * m;
        float rs = rsqrtf(v + 1e-5f);
        float sc = ge[c] * rs;
        coef[192 + c] = sc;
        coef[288 + c] = be[c] - m * sc;
    }
}

// ---------------- h output: h + relu(h_new*sc + sh) ----------------
__global__ __launch_bounds__(256) void h_out_kernel(
    const float* __restrict__ h, const float* __restrict__ h_new,
    const float* __restrict__ coef, float* __restrict__ out, int N)
{
    int idx = blockIdx.x * 256 + threadIdx.x;  // one float4
    int total = N * 24;
    if (idx >= total) return;
    int c4 = (idx % 24) * 4;
    float4 hv = ((const float4*)h)[idx];
    float4 nv = ((const float4*)h_new)[idx];
    float4 o;
    o.x = hv.x + fmaxf(0.f, nv.x * coef[c4 + 0] + coef[96 + c4 + 0]);
    o.y = hv.y + fmaxf(0.f, nv.y * coef[c4 + 1] + coef[96 + c4 + 1]);
    o.z = hv.z + fmaxf(0.f, nv.z * coef[c4 + 2] + coef[96 + c4 + 2]);
    o.w = hv.w + fmaxf(0.f, nv.w * coef[c4 + 3] + coef[96 + c4 + 3]);
    ((float4*)out)[idx] = o;
}

extern "C" void kernel_launch(void* const* d_in, const int* in_sizes, int n_in,
                              void* d_out, int out_size, void* d_ws, size_t ws_size,
                              hipStream_t stream)
{
    const float* h   = (const float*)d_in[0];
    const float* e   = (const float*)d_in[1];
    const int*   src = (const int*)d_in[2];
    const int*   dst = (const int*)d_in[3];
    const float* Aw  = (const float*)d_in[4];
    const float* Ab  = (const float*)d_in[5];
    const float* Bw  = (const float*)d_in[6];
    const float* Bb  = (const float*)d_in[7];
    const float* Cw  = (const float*)d_in[8];
    const float* Cb  = (const float*)d_in[9];
    const float* Dw  = (const float*)d_in[10];
    const float* Db  = (const float*)d_in[11];
    const float* Ewt = (const float*)d_in[12];
    const float* Eb  = (const float*)d_in[13];
    const float* gh  = (const float*)d_in[14];
    const float* bh  = (const float*)d_in[15];
    const float* ge  = (const float*)d_in[16];
    const float* be  = (const float*)d_in[17];

    const int N = in_sizes[0] / 96;
    const int E = in_sizes[2];

    float* ws       = (float*)d_ws;
    float* nodeF    = ws;                               // N*384
    float* node_acc = nodeF + (size_t)N * 384;          // N*192
    float* h_new    = node_acc + (size_t)N * 192;       // N*96
    float* stats    = h_new + (size_t)N * 96;           // 384
    float* coef     = stats + 384;                      // 384
    bf16_t* wb      = (bf16_t*)(coef + 384);            // 5*9216 bf16

    // sort scratch overlapped into dead regions:
    int* cnt    = (int*)node_acc;          // N ints (before node_acc memset)
    int* rowptr = cnt + N;                 // N ints (consumed by scatter as cursor)
    int* perm   = (int*)h_new;             // E ints (dead once h_new_kernel runs)

    // counting sort of edges by dst
    hipMemsetAsync(cnt, 0, (size_t)N * sizeof(int), stream);
    conv_w_kernel<<<dim3(180), dim3(256), 0, stream>>>(Aw, Bw, Cw, Dw, Ewt, wb);
    node_gemm_kernel<<<dim3((N + 63) / 64, 4), dim3(256), 0, stream>>>(h, wb, Ab, Bb, Db, Eb, nodeF, N);
    hist_kernel<<<dim3((E + 255) / 256), dim3(256), 0, stream>>>(dst, cnt, E);
    scan_kernel<<<dim3(1), dim3(1024), 0, stream>>>(cnt, rowptr, N);
    scatter_kernel<<<dim3((E + 255) / 256), dim3(256), 0, stream>>>(dst, rowptr, perm, E);

    hipMemsetAsync(node_acc, 0, (size_t)N * 192 * sizeof(float), stream);
    hipMemsetAsync(stats, 0, 384 * sizeof(float), stream);

    edge_agg_kernel<<<dim3((E + 63) / 64), dim3(256), 0, stream>>>(
        e, src, dst, perm, wb, Cb, nodeF, node_acc, stats, E);
    h_new_kernel<<<dim3((N + 31) / 32), dim3(192), 0, stream>>>(nodeF, node_acc, h_new, stats, N);
    finalize_stats_kernel<<<dim3(1), dim3(192), 0, stream>>>(stats, coef, gh, bh, ge, be, N, E);
    h_out_kernel<<<dim3((N * 24 + 255) / 256), dim3(256), 0, stream>>>(h, h_new, coef, (float*)d_out, N);
    edge_out_kernel<<<dim3((E + 63) / 64), dim3(256), 0, stream>>>(
        e, src, dst, wb, Cb, nodeF, coef, (float*)d_out + (size_t)N * 96, E);
}

// Round 3
// 858.514 us; speedup vs baseline: 1.5837x; 1.3922x over previous
//
#include <hip/hip_runtime.h>
#include <hip/hip_bf16.h>

typedef __bf16 bf16_t;
typedef bf16_t bf16x8 __attribute__((ext_vector_type(8)));
typedef float f32x4 __attribute__((ext_vector_type(4)));

#define LD 104    // padded LDS row stride in bf16 elems (96 + 8)
#define PVLD 194  // bf16 stride for the 64x192 pv tile

__device__ __forceinline__ float bf2f(unsigned short u) {
    return __uint_as_float(((unsigned)u) << 16);
}

// ---------------- weight convert: 5 x [96][96] f32 -> bf16 ----------------
__global__ void conv_w_kernel(const float* __restrict__ A, const float* __restrict__ B,
                              const float* __restrict__ C, const float* __restrict__ Dw,
                              const float* __restrict__ Ew, bf16_t* __restrict__ wb) {
    int i = blockIdx.x * 256 + threadIdx.x;
    if (i >= 5 * 9216) return;
    int m = i / 9216, j = i % 9216;
    const float* p = (m == 0) ? A : (m == 1) ? B : (m == 2) ? C : (m == 3) ? Dw : Ew;
    wb[i] = (bf16_t)p[j];
}

// ---------------- node GEMM: nodeF[n][mat*96+c] = (h @ W^T + b) ----------------
// mat 0..3 -> A,B,Dl,El (wb idx 0,1,3,4). Cb is folded into El's bias (mat 3),
// since e_new = Ce + Dh[src] + (Eh[dst] + Cb).
__global__ __launch_bounds__(256) void node_gemm_kernel(
    const float* __restrict__ h, const bf16_t* __restrict__ wb,
    const float* __restrict__ Ab, const float* __restrict__ Bb,
    const float* __restrict__ Db, const float* __restrict__ Eb,
    const float* __restrict__ Cb,
    float* __restrict__ nodeF, int N)
{
    __shared__ __align__(16) bf16_t sx[64 * LD];
    __shared__ __align__(16) bf16_t sw[96 * LD];
    const int mat = blockIdx.y;
    const int widx = (mat < 2) ? mat : mat + 1;
    const float* bias = (mat == 0) ? Ab : (mat == 1) ? Bb : (mat == 2) ? Db : Eb;
    const int n0 = blockIdx.x * 64;
    const int t = threadIdx.x;

    for (int i = t; i < 64 * 96; i += 256) {
        int r = i / 96, c = i % 96;
        int n = n0 + r;
        float v = (n < N) ? h[n * 96 + c] : 0.f;
        sx[r * LD + c] = (bf16_t)v;
    }
    {
        const unsigned* W4 = (const unsigned*)(wb + widx * 9216);
        for (int i = t; i < 96 * 48; i += 256) {
            int r = i / 48, c = (i % 48) * 2;
            *(unsigned*)&sw[r * LD + c] = W4[i];
        }
    }
    __syncthreads();

    const int w = t >> 6, l = t & 63;
    const int lr = l & 15, lkb = (l >> 4) * 8;
    f32x4 acc[6];
#pragma unroll
    for (int i = 0; i < 6; ++i) acc[i] = (f32x4){0.f, 0.f, 0.f, 0.f};
    const bf16_t* aP = &sx[(w * 16 + lr) * LD + lkb];
#pragma unroll
    for (int kk = 0; kk < 3; ++kk) {
        bf16x8 a = *(const bf16x8*)(aP + kk * 32);
#pragma unroll
        for (int tn = 0; tn < 6; ++tn) {
            bf16x8 b = *(const bf16x8*)(&sw[(tn * 16 + lr) * LD + kk * 32 + lkb]);
            acc[tn] = __builtin_amdgcn_mfma_f32_16x16x32_bf16(a, b, acc[tn], 0, 0, 0);
        }
    }
    const int rowb = (l >> 4) * 4;
#pragma unroll
    for (int tn = 0; tn < 6; ++tn) {
        const int col = tn * 16 + lr;
        float bv = bias[col];
        if (mat == 3) bv += Cb[col];
#pragma unroll
        for (int i = 0; i < 4; ++i) {
            int n = n0 + w * 16 + rowb + i;
            if (n < N) nodeF[n * 384 + mat * 96 + col] = acc[tn][i] + bv;
        }
    }
}

// ---------------- counting sort by dst ----------------
__global__ void hist_kernel(const int* __restrict__ dst, int* __restrict__ cnt, int E) {
    int i = blockIdx.x * 256 + threadIdx.x;
    if (i < E) atomicAdd(&cnt[dst[i]], 1);
}

__global__ __launch_bounds__(1024) void scan_kernel(const int* __restrict__ cnt,
                                                    int* __restrict__ rowptr, int N) {
    __shared__ int wsum[16];
    __shared__ int s_carry;
    const int t = threadIdx.x;
    const int w = t >> 6, l = t & 63;
    if (t == 0) s_carry = 0;
    __syncthreads();
    for (int base = 0; base < N; base += 1024) {
        int v = (base + t < N) ? cnt[base + t] : 0;
        int x = v;
#pragma unroll
        for (int d = 1; d < 64; d <<= 1) {
            int y = __shfl_up(x, d, 64);
            if (l >= d) x += y;
        }
        if (l == 63) wsum[w] = x;
        __syncthreads();
        int carry = s_carry;
        int woff = 0;
        for (int i = 0; i < w; ++i) woff += wsum[i];
        int incl = carry + woff + x;
        if (base + t < N) rowptr[base + t] = incl - v;
        __syncthreads();
        if (t == 1023) s_carry = incl;
    }
}

__global__ void scatter_kernel(const int* __restrict__ dst, int* __restrict__ cursor,
                               int* __restrict__ perm, int E) {
    int i = blockIdx.x * 256 + threadIdx.x;
    if (i < E) {
        int p = atomicAdd(&cursor[dst[i]], 1);
        perm[p] = i;
    }
}

// ---------------- edge aggregation over dst-sorted edges ----------------
// e_new = Ce + Dh[src] + Eh[dst] (Cb pre-folded); sigma; BN-e stats; segmented
// reduction of [sigma*Bh[src], sigma] into node_acc; optional bf16 e_new store.
template <int STORE_EN>
__global__ __launch_bounds__(256) void edge_agg_kernel(
    const float* __restrict__ eP, const int* __restrict__ src, const int* __restrict__ dst,
    const int* __restrict__ perm,
    const bf16_t* __restrict__ wb,
    const float* __restrict__ nodeF, float* __restrict__ node_acc,
    float* __restrict__ stats, bf16_t* __restrict__ e_new_bf, int E)
{
    __shared__ __align__(16) char smem[64 * LD * 2 + 96 * LD * 2];  // 33280 B
    bf16_t* se  = (bf16_t*)smem;                    // [64][LD]
    bf16_t* sw  = (bf16_t*)(smem + 64 * LD * 2);    // [96][LD]
    bf16_t* pvb = (bf16_t*)smem;                    // [64][PVLD] = 24832 B (reuse)
    __shared__ int seid[64], ssrc[64], sdst[64];
    __shared__ float bns[96], bnq[96];

    const int t = threadIdx.x;
    const int e0 = blockIdx.x * 64;

    if (t < 64) {
        int ge = e0 + t;
        int eid = (ge < E) ? perm[ge] : -1;
        seid[t] = eid;
        ssrc[t] = (eid >= 0) ? src[eid] : 0;
        sdst[t] = (eid >= 0) ? dst[eid] : 0;
    }
    if (t >= 64 && t < 160) { bns[t - 64] = 0.f; bnq[t - 64] = 0.f; }
    __syncthreads();

    {
        const unsigned* W4 = (const unsigned*)(wb + 2 * 9216);  // C_w
        for (int i = t; i < 96 * 48; i += 256) {
            int r = i / 48, c = (i % 48) * 2;
            *(unsigned*)&sw[r * LD + c] = W4[i];
        }
    }
    for (int i = t; i < 64 * 24; i += 256) {
        int r = i / 24, c4 = i % 24;
        int eid = seid[r];
        float4 v = (eid >= 0) ? ((const float4*)eP)[(size_t)eid * 24 + c4]
                              : make_float4(0.f, 0.f, 0.f, 0.f);
        bf16_t* p = &se[r * LD + c4 * 4];
        p[0] = (bf16_t)v.x; p[1] = (bf16_t)v.y; p[2] = (bf16_t)v.z; p[3] = (bf16_t)v.w;
    }
    __syncthreads();

    const int w = t >> 6, l = t & 63;
    const int lr = l & 15, lkb = (l >> 4) * 8;
    f32x4 acc[6];
#pragma unroll
    for (int i = 0; i < 6; ++i) acc[i] = (f32x4){0.f, 0.f, 0.f, 0.f};
    const bf16_t* aP = &se[(w * 16 + lr) * LD + lkb];
#pragma unroll
    for (int kk = 0; kk < 3; ++kk) {
        bf16x8 a = *(const bf16x8*)(aP + kk * 32);
#pragma unroll
        for (int tn = 0; tn < 6; ++tn) {
            bf16x8 b = *(const bf16x8*)(&sw[(tn * 16 + lr) * LD + kk * 32 + lkb]);
            acc[tn] = __builtin_amdgcn_mfma_f32_16x16x32_bf16(a, b, acc[tn], 0, 0, 0);
        }
    }

    __syncthreads();  // se/sw reads done; pvb may overwrite

    const int rowb = (l >> 4) * 4;
#pragma unroll
    for (int tn = 0; tn < 6; ++tn) {
        const int col = tn * 16 + lr;
        float ls = 0.f, lq = 0.f;
        float ehv = 0.f;
        int prevdd = -1;
#pragma unroll
        for (int i = 0; i < 4; ++i) {
            const int r = w * 16 + rowb + i;
            const int eid = seid[r];
            const bool ok = (eid >= 0);
            const int s = ssrc[r], dd = sdst[r];
            float sg = 0.f, sh = 0.f;
            if (ok) {
                if (dd != prevdd) { ehv = nodeF[dd * 384 + 288 + col]; prevdd = dd; }
                float en = acc[tn][i] + nodeF[s * 384 + 192 + col] + ehv;
                sg = 1.f / (1.f + __expf(-en));
                sh = sg * nodeF[s * 384 + 96 + col];
                ls += en; lq += en * en;
                if (STORE_EN) e_new_bf[(size_t)eid * 96 + col] = (bf16_t)en;
            }
            pvb[r * PVLD + col] = (bf16_t)sh;
            pvb[r * PVLD + 96 + col] = (bf16_t)sg;
        }
        ls += __shfl_xor(ls, 16, 64); lq += __shfl_xor(lq, 16, 64);
        ls += __shfl_xor(ls, 32, 64); lq += __shfl_xor(lq, 32, 64);
        if (l < 16) {
            atomicAdd(&bns[col], ls);
            atomicAdd(&bnq[col], lq);
        }
    }
    __syncthreads();  // pvb complete + bns/bnq complete

    if (t < 192) {
        float run = 0.f;
        int prev = sdst[0];
        for (int r = 0; r < 64; ++r) {
            int d = sdst[r];
            if (d != prev) {
                unsafeAtomicAdd(&node_acc[(size_t)prev * 192 + t], run);
                run = 0.f;
                prev = d;
            }
            run += bf2f(*(const unsigned short*)&pvb[r * PVLD + t]);
        }
        unsafeAtomicAdd(&node_acc[(size_t)prev * 192 + t], run);
    }
    if (t < 96) {
        unsafeAtomicAdd(&stats[192 + t], bns[t]);
        unsafeAtomicAdd(&stats[288 + t], bnq[t]);
    }
}

// ---------------- streaming edge output: e_out = e + relu(en*sc + sh) ----------------
__global__ __launch_bounds__(256) void edge_out_fast_kernel(
    const float* __restrict__ eP, const bf16_t* __restrict__ e_new_bf,
    const float* __restrict__ coef, float* __restrict__ eout, long long total4)
{
    long long idx = (long long)blockIdx.x * 256 + threadIdx.x;
    if (idx >= total4) return;
    int c4 = (int)(idx % 24) * 4;
    float4 res = ((const float4*)eP)[idx];
    ushort4 nb = ((const ushort4*)e_new_bf)[idx];
    float4 o;
    o.x = res.x + fmaxf(0.f, bf2f(nb.x) * coef[192 + c4 + 0] + coef[288 + c4 + 0]);
    o.y = res.y + fmaxf(0.f, bf2f(nb.y) * coef[192 + c4 + 1] + coef[288 + c4 + 1]);
    o.z = res.z + fmaxf(0.f, bf2f(nb.z) * coef[192 + c4 + 2] + coef[288 + c4 + 2]);
    o.w = res.w + fmaxf(0.f, bf2f(nb.w) * coef[192 + c4 + 3] + coef[288 + c4 + 3]);
    ((float4*)eout)[idx] = o;
}

// ---------------- fallback edge output (recompute path) ----------------
__global__ __launch_bounds__(256) void edge_out_kernel(
    const float* __restrict__ eP, const int* __restrict__ src, const int* __restrict__ dst,
    const bf16_t* __restrict__ wb,
    const float* __restrict__ nodeF, const float* __restrict__ coef,
    float* __restrict__ eout, int E)
{
    __shared__ __align__(16) bf16_t se[64 * LD];
    __shared__ __align__(16) bf16_t sw[96 * LD];
    __shared__ int ssrc[64], sdst[64];
    const int t = threadIdx.x;
    const int e0 = blockIdx.x * 64;

    {
        const unsigned* W4 = (const unsigned*)(wb + 2 * 9216);  // C_w
        for (int i = t; i < 96 * 48; i += 256) {
            int r = i / 48, c = (i % 48) * 2;
            *(unsigned*)&sw[r * LD + c] = W4[i];
        }
    }
    for (int i = t; i < 64 * 96; i += 256) {
        int r = i / 96, c = i % 96;
        int ge = e0 + r;
        float v = (ge < E) ? eP[ge * 96 + c] : 0.f;
        se[r * LD + c] = (bf16_t)v;
    }
    if (t < 64) {
        int ge = e0 + t;
        ssrc[t] = (ge < E) ? src[ge] : 0;
        sdst[t] = (ge < E) ? dst[ge] : 0;
    }
    __syncthreads();

    const int w = t >> 6, l = t & 63;
    const int lr = l & 15, lkb = (l >> 4) * 8;
    f32x4 acc[6];
#pragma unroll
    for (int i = 0; i < 6; ++i) acc[i] = (f32x4){0.f, 0.f, 0.f, 0.f};
    const bf16_t* aP = &se[(w * 16 + lr) * LD + lkb];
#pragma unroll
    for (int kk = 0; kk < 3; ++kk) {
        bf16x8 a = *(const bf16x8*)(aP + kk * 32);
#pragma unroll
        for (int tn = 0; tn < 6; ++tn) {
            bf16x8 b = *(const bf16x8*)(&sw[(tn * 16 + lr) * LD + kk * 32 + lkb]);
            acc[tn] = __builtin_amdgcn_mfma_f32_16x16x32_bf16(a, b, acc[tn], 0, 0, 0);
        }
    }

    const int rowb = (l >> 4) * 4;
#pragma unroll
    for (int tn = 0; tn < 6; ++tn) {
        const int col = tn * 16 + lr;
        const float sc_e = coef[192 + col];
        const float sh_e = coef[288 + col];
#pragma unroll
        for (int i = 0; i < 4; ++i) {
            const int r = w * 16 + rowb + i;
            const int ge = e0 + r;
            if (ge < E) {
                const int s = ssrc[r], dd = sdst[r];
                float en = acc[tn][i] + nodeF[s * 384 + 192 + col]
                         + nodeF[dd * 384 + 288 + col];
                float res = eP[ge * 96 + col];
                eout[ge * 96 + col] = res + fmaxf(0.f, en * sc_e + sh_e);
            }
        }
    }
}

// ---------------- h_new + BN-h stats ----------------
__global__ __launch_bounds__(192) void h_new_kernel(
    const float* __restrict__ nodeF, const float* __restrict__ node_acc,
    float* __restrict__ h_new, float* __restrict__ stats, int N)
{
    __shared__ float bs[192], bq[192];
    const int t = threadIdx.x;
    const int col = t % 96, half = t / 96;
    const int n0 = blockIdx.x * 32;
    float ls = 0.f, lq = 0.f;
    for (int r = half; r < 32; r += 2) {
        int n = n0 + r;
        if (n >= N) break;
        float ssum = node_acc[n * 192 + 96 + col];
        float shh = node_acc[n * 192 + col];
        float v = nodeF[n * 384 + col] + shh / (ssum + 1e-6f);
        h_new[n * 96 + col] = v;
        ls += v; lq += v * v;
    }
    bs[t] = ls; bq[t] = lq;
    __syncthreads();
    if (t < 96) {
        unsafeAtomicAdd(&stats[t], bs[t] + bs[t + 96]);
        unsafeAtomicAdd(&stats[96 + t], bq[t] + bq[t + 96]);
    }
}

// ---------------- stats -> scale/shift coefs ----------------
__global__ void finalize_stats_kernel(const float* __restrict__ stats, float* __restrict__ coef,
                                      const float* __restrict__ gh, const float* __restrict__ bh,
                                      const float* __restrict__ ge, const float* __restrict__ be,
                                      int N, int E)
{
    int t = threadIdx.x;
    if (t < 96) {
        float m = stats[t] / (float)N;
        float v = stats[96 + t] / (float)N - m * m;
        float rs = rsqrtf(v + 1e-5f);
        float sc = gh[t] * rs;
        coef[t] = sc;
        coef[96 + t] = bh[t] - m * sc;
    } else if (t < 192) {
        int c = t - 96;
        float m = stats[192 + c] / (float)E;
        float v = stats[288 + c] / (float)E - m * m;
        float rs = rsqrtf(v + 1e-5f);
        float sc = ge[c] * rs;
        coef[192 + c] = sc;
        coef[288 + c] = be[c] - m * sc;
    }
}

// ---------------- h output: h + relu(h_new*sc + sh) ----------------
__global__ __launch_bounds__(256) void h_out_kernel(
    const float* __restrict__ h, const float* __restrict__ h_new,
    const float* __restrict__ coef, float* __restrict__ out, int N)
{
    int idx = blockIdx.x * 256 + threadIdx.x;  // one float4
    int total = N * 24;
    if (idx >= total) return;
    int c4 = (idx % 24) * 4;
    float4 hv = ((const float4*)h)[idx];
    float4 nv = ((const float4*)h_new)[idx];
    float4 o;
    o.x = hv.x + fmaxf(0.f, nv.x * coef[c4 + 0] + coef[96 + c4 + 0]);
    o.y = hv.y + fmaxf(0.f, nv.y * coef[c4 + 1] + coef[96 + c4 + 1]);
    o.z = hv.z + fmaxf(0.f, nv.z * coef[c4 + 2] + coef[96 + c4 + 2]);
    o.w = hv.w + fmaxf(0.f, nv.w * coef[c4 + 3] + coef[96 + c4 + 3]);
    ((float4*)out)[idx] = o;
}

extern "C" void kernel_launch(void* const* d_in, const int* in_sizes, int n_in,
                              void* d_out, int out_size, void* d_ws, size_t ws_size,
                              hipStream_t stream)
{
    const float* h   = (const float*)d_in[0];
    const float* e   = (const float*)d_in[1];
    const int*   src = (const int*)d_in[2];
    const int*   dst = (const int*)d_in[3];
    const float* Aw  = (const float*)d_in[4];
    const float* Ab  = (const float*)d_in[5];
    const float* Bw  = (const float*)d_in[6];
    const float* Bb  = (const float*)d_in[7];
    const float* Cw  = (const float*)d_in[8];
    const float* Cb  = (const float*)d_in[9];
    const float* Dw  = (const float*)d_in[10];
    const float* Db  = (const float*)d_in[11];
    const float* Ewt = (const float*)d_in[12];
    const float* Eb  = (const float*)d_in[13];
    const float* gh  = (const float*)d_in[14];
    const float* bh  = (const float*)d_in[15];
    const float* ge  = (const float*)d_in[16];
    const float* be  = (const float*)d_in[17];

    const int N = in_sizes[0] / 96;
    const int E = in_sizes[2];

    float* ws       = (float*)d_ws;
    float* nodeF    = ws;                               // N*384 f32
    float* node_acc = nodeF + (size_t)N * 384;          // N*192 f32
    float* h_new    = node_acc + (size_t)N * 192;       // N*96 f32
    float* stats    = h_new + (size_t)N * 96;           // 384 f32
    float* coef     = stats + 384;                      // 384 f32
    bf16_t* wb      = (bf16_t*)(coef + 384);            // 5*9216 bf16
    bf16_t* e_new_bf = wb + 5 * 9216;                   // E*96 bf16 (optional)

    const size_t base_bytes = (size_t)((char*)e_new_bf - (char*)d_ws);
    const bool store_en = (ws_size >= base_bytes + (size_t)E * 96 * 2);

    // sort scratch overlapped into dead regions:
    int* cnt    = (int*)node_acc;          // N ints (before node_acc memset)
    int* rowptr = cnt + N;                 // N ints (consumed by scatter as cursor)
    int* perm   = (int*)h_new;             // E ints (dead once h_new_kernel runs)

    hipMemsetAsync(cnt, 0, (size_t)N * sizeof(int), stream);
    conv_w_kernel<<<dim3(180), dim3(256), 0, stream>>>(Aw, Bw, Cw, Dw, Ewt, wb);
    node_gemm_kernel<<<dim3((N + 63) / 64, 4), dim3(256), 0, stream>>>(
        h, wb, Ab, Bb, Db, Eb, Cb, nodeF, N);
    hist_kernel<<<dim3((E + 255) / 256), dim3(256), 0, stream>>>(dst, cnt, E);
    scan_kernel<<<dim3(1), dim3(1024), 0, stream>>>(cnt, rowptr, N);
    scatter_kernel<<<dim3((E + 255) / 256), dim3(256), 0, stream>>>(dst, rowptr, perm, E);

    hipMemsetAsync(node_acc, 0, (size_t)N * 192 * sizeof(float), stream);
    hipMemsetAsync(stats, 0, 384 * sizeof(float), stream);

    if (store_en) {
        edge_agg_kernel<1><<<dim3((E + 63) / 64), dim3(256), 0, stream>>>(
            e, src, dst, perm, wb, nodeF, node_acc, stats, e_new_bf, E);
    } else {
        edge_agg_kernel<0><<<dim3((E + 63) / 64), dim3(256), 0, stream>>>(
            e, src, dst, perm, wb, nodeF, node_acc, stats, nullptr, E);
    }
    h_new_kernel<<<dim3((N + 31) / 32), dim3(192), 0, stream>>>(nodeF, node_acc, h_new, stats, N);
    finalize_stats_kernel<<<dim3(1), dim3(192), 0, stream>>>(stats, coef, gh, bh, ge, be, N, E);
    h_out_kernel<<<dim3((N * 24 + 255) / 256), dim3(256), 0, stream>>>(h, h_new, coef, (float*)d_out, N);

    if (store_en) {
        long long total4 = (long long)E * 24;
        edge_out_fast_kernel<<<dim3((unsigned)((total4 + 255) / 256)), dim3(256), 0, stream>>>(
            e, e_new_bf, coef, (float*)d_out + (size_t)N * 96, total4);
    } else {
        edge_out_kernel<<<dim3((E + 63) / 64), dim3(256), 0, stream>>>(
            e, src, dst, wb, nodeF, coef, (float*)d_out + (size_t)N * 96, E);
    }
}

// Round 4
// 821.705 us; speedup vs baseline: 1.6546x; 1.0448x over previous
//
#include <hip/hip_runtime.h>
#include <hip/hip_bf16.h>

typedef __bf16 bf16_t;
typedef bf16_t bf16x8 __attribute__((ext_vector_type(8)));
typedef float f32x4 __attribute__((ext_vector_type(4)));

#define LD 104    // padded LDS row stride in bf16 elems (96 + 8)
#define PVLD 194  // bf16 stride for the 64x192 pv tile (4-row stride -> +4 banks)

__device__ __forceinline__ float bf2f(unsigned short u) {
    return __uint_as_float(((unsigned)u) << 16);
}

// ---------------- weight convert: 5 x [96][96] f32 -> bf16 ----------------
__global__ void conv_w_kernel(const float* __restrict__ A, const float* __restrict__ B,
                              const float* __restrict__ C, const float* __restrict__ Dw,
                              const float* __restrict__ Ew, bf16_t* __restrict__ wb) {
    int i = blockIdx.x * 256 + threadIdx.x;
    if (i >= 5 * 9216) return;
    int m = i / 9216, j = i % 9216;
    const float* p = (m == 0) ? A : (m == 1) ? B : (m == 2) ? C : (m == 3) ? Dw : Ew;
    wb[i] = (bf16_t)p[j];
}

// ---------------- pack C_w into per-lane MFMA B-fragment order ----------------
// wpack[(tn*3+kk)*64 + l][j] = Cw[tn*16 + (l&15)][kk*32 + (l>>4)*8 + j]
__global__ void pack_cw_kernel(const float* __restrict__ Cw, bf16_t* __restrict__ wpack) {
    int idx = blockIdx.x * 256 + threadIdx.x;
    if (idx >= 18 * 64) return;
    int frag = idx >> 6, l = idx & 63;
    int tn = frag / 3, kk = frag % 3;
    int row = tn * 16 + (l & 15);
    int c0 = kk * 32 + (l >> 4) * 8;
    bf16_t* o = wpack + (size_t)idx * 8;
#pragma unroll
    for (int j = 0; j < 8; ++j) o[j] = (bf16_t)Cw[row * 96 + c0 + j];
}

// ---------------- node GEMM: nodeF[n][mat*96+c] = (h @ W^T + b) ----------------
// mat 0..3 -> A,B,Dl,El (wb idx 0,1,3,4). Cb folded into El's bias (mat 3).
__global__ __launch_bounds__(256) void node_gemm_kernel(
    const float* __restrict__ h, const bf16_t* __restrict__ wb,
    const float* __restrict__ Ab, const float* __restrict__ Bb,
    const float* __restrict__ Db, const float* __restrict__ Eb,
    const float* __restrict__ Cb,
    float* __restrict__ nodeF, int N)
{
    __shared__ __align__(16) bf16_t sx[64 * LD];
    __shared__ __align__(16) bf16_t sw[96 * LD];
    const int mat = blockIdx.y;
    const int widx = (mat < 2) ? mat : mat + 1;
    const float* bias = (mat == 0) ? Ab : (mat == 1) ? Bb : (mat == 2) ? Db : Eb;
    const int n0 = blockIdx.x * 64;
    const int t = threadIdx.x;

    for (int i = t; i < 64 * 96; i += 256) {
        int r = i / 96, c = i % 96;
        int n = n0 + r;
        float v = (n < N) ? h[n * 96 + c] : 0.f;
        sx[r * LD + c] = (bf16_t)v;
    }
    {
        const unsigned* W4 = (const unsigned*)(wb + widx * 9216);
        for (int i = t; i < 96 * 48; i += 256) {
            int r = i / 48, c = (i % 48) * 2;
            *(unsigned*)&sw[r * LD + c] = W4[i];
        }
    }
    __syncthreads();

    const int w = t >> 6, l = t & 63;
    const int lr = l & 15, lkb = (l >> 4) * 8;
    f32x4 acc[6];
#pragma unroll
    for (int i = 0; i < 6; ++i) acc[i] = (f32x4){0.f, 0.f, 0.f, 0.f};
    const bf16_t* aP = &sx[(w * 16 + lr) * LD + lkb];
#pragma unroll
    for (int kk = 0; kk < 3; ++kk) {
        bf16x8 a = *(const bf16x8*)(aP + kk * 32);
#pragma unroll
        for (int tn = 0; tn < 6; ++tn) {
            bf16x8 b = *(const bf16x8*)(&sw[(tn * 16 + lr) * LD + kk * 32 + lkb]);
            acc[tn] = __builtin_amdgcn_mfma_f32_16x16x32_bf16(a, b, acc[tn], 0, 0, 0);
        }
    }
    const int rowb = (l >> 4) * 4;
#pragma unroll
    for (int tn = 0; tn < 6; ++tn) {
        const int col = tn * 16 + lr;
        float bv = bias[col];
        if (mat == 3) bv += Cb[col];
#pragma unroll
        for (int i = 0; i < 4; ++i) {
            int n = n0 + w * 16 + rowb + i;
            if (n < N) nodeF[n * 384 + mat * 96 + col] = acc[tn][i] + bv;
        }
    }
}

// ---------------- counting sort by dst ----------------
__global__ void hist_kernel(const int* __restrict__ dst, int* __restrict__ cnt, int E) {
    int i = blockIdx.x * 256 + threadIdx.x;
    if (i < E) atomicAdd(&cnt[dst[i]], 1);
}

__global__ __launch_bounds__(1024) void scan_kernel(const int* __restrict__ cnt,
                                                    int* __restrict__ rowptr, int N) {
    __shared__ int wsum[16];
    __shared__ int s_carry;
    const int t = threadIdx.x;
    const int w = t >> 6, l = t & 63;
    if (t == 0) s_carry = 0;
    __syncthreads();
    for (int base = 0; base < N; base += 1024) {
        int v = (base + t < N) ? cnt[base + t] : 0;
        int x = v;
#pragma unroll
        for (int d = 1; d < 64; d <<= 1) {
            int y = __shfl_up(x, d, 64);
            if (l >= d) x += y;
        }
        if (l == 63) wsum[w] = x;
        __syncthreads();
        int carry = s_carry;
        int woff = 0;
        for (int i = 0; i < w; ++i) woff += wsum[i];
        int incl = carry + woff + x;
        if (base + t < N) rowptr[base + t] = incl - v;
        __syncthreads();
        if (t == 1023) s_carry = incl;
    }
}

__global__ void scatter_kernel(const int* __restrict__ dst, int* __restrict__ cursor,
                               int* __restrict__ perm, int E) {
    int i = blockIdx.x * 256 + threadIdx.x;
    if (i < E) {
        int p = atomicAdd(&cursor[dst[i]], 1);
        perm[p] = i;
    }
}

// ---------------- edge aggregation over dst-sorted edges ----------------
// e_new = Ce + Dh[src] + (Eh[dst]+Cb); sigma; BN-e stats; segmented reduction of
// [sigma*Bh[src], sigma] into node_acc; optional bf16 e_new store.
// A-fragment loaded directly from global e; B-fragment from pre-packed wpack.
template <int STORE_EN>
__global__ __launch_bounds__(256) void edge_agg_kernel(
    const float* __restrict__ eP, const int* __restrict__ src, const int* __restrict__ dst,
    const int* __restrict__ perm,
    const bf16_t* __restrict__ wpack,
    const float* __restrict__ nodeF, float* __restrict__ node_acc,
    float* __restrict__ stats, bf16_t* __restrict__ e_new_bf, int E)
{
    __shared__ __align__(16) bf16_t pvb[64 * PVLD];   // 24832 B
    __shared__ int seid[64], ssrc[64], sdst[64];
    __shared__ float bns[96], bnq[96];

    const int t = threadIdx.x;
    const int e0 = blockIdx.x * 64;

    if (t < 64) {
        int ge = e0 + t;
        int eid = (ge < E) ? perm[ge] : -1;
        seid[t] = eid;
        ssrc[t] = (eid >= 0) ? src[eid] : 0;
        sdst[t] = (eid >= 0) ? dst[eid] : 0;
    }
    if (t >= 64 && t < 160) { bns[t - 64] = 0.f; bnq[t - 64] = 0.f; }
    __syncthreads();

    const int w = t >> 6, l = t & 63;
    const int lr = l & 15, lkb = (l >> 4) * 8;

    // ---- A-fragment: direct global load of this lane's edge row, f32 -> bf16 ----
    int eida = seid[w * 16 + lr];
    if (eida < 0) eida = 0;
    const float* arow = eP + (size_t)eida * 96 + lkb;
    float4 af[6];
#pragma unroll
    for (int kk = 0; kk < 3; ++kk) {
        af[kk * 2]     = *(const float4*)(arow + kk * 32);
        af[kk * 2 + 1] = *(const float4*)(arow + kk * 32 + 4);
    }
    bf16x8 a[3];
#pragma unroll
    for (int kk = 0; kk < 3; ++kk) {
        a[kk][0] = (bf16_t)af[kk * 2].x;   a[kk][1] = (bf16_t)af[kk * 2].y;
        a[kk][2] = (bf16_t)af[kk * 2].z;   a[kk][3] = (bf16_t)af[kk * 2].w;
        a[kk][4] = (bf16_t)af[kk * 2 + 1].x; a[kk][5] = (bf16_t)af[kk * 2 + 1].y;
        a[kk][6] = (bf16_t)af[kk * 2 + 1].z; a[kk][7] = (bf16_t)af[kk * 2 + 1].w;
    }

    // ---- MFMA: B-fragments streamed from wpack (L1-hot) ----
    f32x4 acc[6];
#pragma unroll
    for (int i = 0; i < 6; ++i) acc[i] = (f32x4){0.f, 0.f, 0.f, 0.f};
    const bf16x8* wp = (const bf16x8*)wpack;
#pragma unroll
    for (int kk = 0; kk < 3; ++kk) {
#pragma unroll
        for (int tn = 0; tn < 6; ++tn) {
            bf16x8 b = wp[(tn * 3 + kk) * 64 + l];
            acc[tn] = __builtin_amdgcn_mfma_f32_16x16x32_bf16(a[kk], b, acc[tn], 0, 0, 0);
        }
    }

    // ---- gather + sigma + stats + pv, two batches of 3 tn for bounded VGPR ----
    const int rowb = (l >> 4) * 4;
    int eid_r[4], s_r[4], d_r[4];
    const float* baseS[4];
    const float* baseD[4];
#pragma unroll
    for (int i = 0; i < 4; ++i) {
        const int r = w * 16 + rowb + i;
        eid_r[i] = seid[r];
        s_r[i] = ssrc[r];
        d_r[i] = sdst[r];
        baseS[i] = nodeF + (size_t)s_r[i] * 384 + lr;
        baseD[i] = nodeF + (size_t)d_r[i] * 384 + lr;
    }

#pragma unroll
    for (int half = 0; half < 2; ++half) {
        float dh[3][4], eh[3][4], bh[3][4];
#pragma unroll
        for (int q = 0; q < 3; ++q) {
            const int tn = half * 3 + q;
#pragma unroll
            for (int i = 0; i < 4; ++i) {
                dh[q][i] = baseS[i][192 + tn * 16];
                eh[q][i] = baseD[i][288 + tn * 16];
                bh[q][i] = baseS[i][96 + tn * 16];
            }
        }
#pragma unroll
        for (int q = 0; q < 3; ++q) {
            const int tn = half * 3 + q;
            const int col = tn * 16 + lr;
            float ls = 0.f, lq = 0.f;
#pragma unroll
            for (int i = 0; i < 4; ++i) {
                const int r = w * 16 + rowb + i;
                const bool ok = (eid_r[i] >= 0);
                float en = acc[tn][i] + dh[q][i] + eh[q][i];
                float sg = 0.f, sh = 0.f;
                if (ok) {
                    sg = 1.f / (1.f + __expf(-en));
                    sh = sg * bh[q][i];
                    ls += en; lq += en * en;
                    if (STORE_EN) e_new_bf[(size_t)eid_r[i] * 96 + col] = (bf16_t)en;
                }
                pvb[r * PVLD + col] = (bf16_t)sh;
                pvb[r * PVLD + 96 + col] = (bf16_t)sg;
            }
            ls += __shfl_xor(ls, 16, 64); lq += __shfl_xor(lq, 16, 64);
            ls += __shfl_xor(ls, 32, 64); lq += __shfl_xor(lq, 32, 64);
            if (l < 16) {
                atomicAdd(&bns[col], ls);
                atomicAdd(&bnq[col], lq);
            }
        }
    }
    __syncthreads();  // pvb complete + bns/bnq complete

    if (t < 192) {
        float run = 0.f;
        int prev = sdst[0];
        for (int r = 0; r < 64; ++r) {
            int d = sdst[r];
            if (d != prev) {
                unsafeAtomicAdd(&node_acc[(size_t)prev * 192 + t], run);
                run = 0.f;
                prev = d;
            }
            run += bf2f(*(const unsigned short*)&pvb[r * PVLD + t]);
        }
        unsafeAtomicAdd(&node_acc[(size_t)prev * 192 + t], run);
    }
    if (t < 96) {
        unsafeAtomicAdd(&stats[192 + t], bns[t]);
        unsafeAtomicAdd(&stats[288 + t], bnq[t]);
    }
}

// ---------------- streaming edge output: e_out = e + relu(en*sc + sh) ----------------
__global__ __launch_bounds__(256) void edge_out_fast_kernel(
    const float* __restrict__ eP, const bf16_t* __restrict__ e_new_bf,
    const float* __restrict__ coef, float* __restrict__ eout, long long total4)
{
    long long idx = (long long)blockIdx.x * 256 + threadIdx.x;
    if (idx >= total4) return;
    int c4 = (int)(idx % 24) * 4;
    float4 res = ((const float4*)eP)[idx];
    ushort4 nb = ((const ushort4*)e_new_bf)[idx];
    float4 o;
    o.x = res.x + fmaxf(0.f, bf2f(nb.x) * coef[192 + c4 + 0] + coef[288 + c4 + 0]);
    o.y = res.y + fmaxf(0.f, bf2f(nb.y) * coef[192 + c4 + 1] + coef[288 + c4 + 1]);
    o.z = res.z + fmaxf(0.f, bf2f(nb.z) * coef[192 + c4 + 2] + coef[288 + c4 + 2]);
    o.w = res.w + fmaxf(0.f, bf2f(nb.w) * coef[192 + c4 + 3] + coef[288 + c4 + 3]);
    ((float4*)eout)[idx] = o;
}

// ---------------- fallback edge output (recompute path) ----------------
__global__ __launch_bounds__(256) void edge_out_kernel(
    const float* __restrict__ eP, const int* __restrict__ src, const int* __restrict__ dst,
    const bf16_t* __restrict__ wb,
    const float* __restrict__ nodeF, const float* __restrict__ coef,
    float* __restrict__ eout, int E)
{
    __shared__ __align__(16) bf16_t se[64 * LD];
    __shared__ __align__(16) bf16_t sw[96 * LD];
    __shared__ int ssrc[64], sdst[64];
    const int t = threadIdx.x;
    const int e0 = blockIdx.x * 64;

    {
        const unsigned* W4 = (const unsigned*)(wb + 2 * 9216);  // C_w
        for (int i = t; i < 96 * 48; i += 256) {
            int r = i / 48, c = (i % 48) * 2;
            *(unsigned*)&sw[r * LD + c] = W4[i];
        }
    }
    for (int i = t; i < 64 * 96; i += 256) {
        int r = i / 96, c = i % 96;
        int ge = e0 + r;
        float v = (ge < E) ? eP[ge * 96 + c] : 0.f;
        se[r * LD + c] = (bf16_t)v;
    }
    if (t < 64) {
        int ge = e0 + t;
        ssrc[t] = (ge < E) ? src[ge] : 0;
        sdst[t] = (ge < E) ? dst[ge] : 0;
    }
    __syncthreads();

    const int w = t >> 6, l = t & 63;
    const int lr = l & 15, lkb = (l >> 4) * 8;
    f32x4 acc[6];
#pragma unroll
    for (int i = 0; i < 6; ++i) acc[i] = (f32x4){0.f, 0.f, 0.f, 0.f};
    const bf16_t* aP = &se[(w * 16 + lr) * LD + lkb];
#pragma unroll
    for (int kk = 0; kk < 3; ++kk) {
        bf16x8 a = *(const bf16x8*)(aP + kk * 32);
#pragma unroll
        for (int tn = 0; tn < 6; ++tn) {
            bf16x8 b = *(const bf16x8*)(&sw[(tn * 16 + lr) * LD + kk * 32 + lkb]);
            acc[tn] = __builtin_amdgcn_mfma_f32_16x16x32_bf16(a, b, acc[tn], 0, 0, 0);
        }
    }

    const int rowb = (l >> 4) * 4;
#pragma unroll
    for (int tn = 0; tn < 6; ++tn) {
        const int col = tn * 16 + lr;
        const float sc_e = coef[192 + col];
        const float sh_e = coef[288 + col];
#pragma unroll
        for (int i = 0; i < 4; ++i) {
            const int r = w * 16 + rowb + i;
            const int ge = e0 + r;
            if (ge < E) {
                const int s = ssrc[r], dd = sdst[r];
                float en = acc[tn][i] + nodeF[s * 384 + 192 + col]
                         + nodeF[dd * 384 + 288 + col];
                float res = eP[ge * 96 + col];
                eout[ge * 96 + col] = res + fmaxf(0.f, en * sc_e + sh_e);
            }
        }
    }
}

// ---------------- h_new + BN-h stats ----------------
__global__ __launch_bounds__(192) void h_new_kernel(
    const float* __restrict__ nodeF, const float* __restrict__ node_acc,
    float* __restrict__ h_new, float* __restrict__ stats, int N)
{
    __shared__ float bs[192], bq[192];
    const int t = threadIdx.x;
    const int col = t % 96, half = t / 96;
    const int n0 = blockIdx.x * 32;
    float ls = 0.f, lq = 0.f;
    for (int r = half; r < 32; r += 2) {
        int n = n0 + r;
        if (n >= N) break;
        float ssum = node_acc[n * 192 + 96 + col];
        float shh = node_acc[n * 192 + col];
        float v = nodeF[n * 384 + col] + shh / (ssum + 1e-6f);
        h_new[n * 96 + col] = v;
        ls += v; lq += v * v;
    }
    bs[t] = ls; bq[t] = lq;
    __syncthreads();
    if (t < 96) {
        unsafeAtomicAdd(&stats[t], bs[t] + bs[t + 96]);
        unsafeAtomicAdd(&stats[96 + t], bq[t] + bq[t + 96]);
    }
}

// ---------------- stats -> scale/shift coefs ----------------
__global__ void finalize_stats_kernel(const float* __restrict__ stats, float* __restrict__ coef,
                                      const float* __restrict__ gh, const float* __restrict__ bh,
                                      const float* __restrict__ ge, const float* __restrict__ be,
                                      int N, int E)
{
    int t = threadIdx.x;
    if (t < 96) {
        float m = stats[t] / (float)N;
        float v = stats[96 + t] / (float)N - m * m;
        float rs = rsqrtf(v + 1e-5f);
        float sc = gh[t] * rs;
        coef[t] = sc;
        coef[96 + t] = bh[t] - m * sc;
    } else if (t < 192) {
        int c = t - 96;
        float m = stats[192 + c] / (float)E;
        float v = stats[288 + c] / (float)E - m * m;
        float rs = rsqrtf(v + 1e-5f);
        float sc = ge[c] * rs;
        coef[192 + c] = sc;
        coef[288 + c] = be[c] - m * sc;
    }
}

// ---------------- h output: h + relu(h_new*sc + sh) ----------------
__global__ __launch_bounds__(256) void h_out_kernel(
    const float* __restrict__ h, const float* __restrict__ h_new,
    const float* __restrict__ coef, float* __restrict__ out, int N)
{
    int idx = blockIdx.x * 256 + threadIdx.x;  // one float4
    int total = N * 24;
    if (idx >= total) return;
    int c4 = (idx % 24) * 4;
    float4 hv = ((const float4*)h)[idx];
    float4 nv = ((const float4*)h_new)[idx];
    float4 o;
    o.x = hv.x + fmaxf(0.f, nv.x * coef[c4 + 0] + coef[96 + c4 + 0]);
    o.y = hv.y + fmaxf(0.f, nv.y * coef[c4 + 1] + coef[96 + c4 + 1]);
    o.z = hv.z + fmaxf(0.f, nv.z * coef[c4 + 2] + coef[96 + c4 + 2]);
    o.w = hv.w + fmaxf(0.f, nv.w * coef[c4 + 3] + coef[96 + c4 + 3]);
    ((float4*)out)[idx] = o;
}

extern "C" void kernel_launch(void* const* d_in, const int* in_sizes, int n_in,
                              void* d_out, int out_size, void* d_ws, size_t ws_size,
                              hipStream_t stream)
{
    const float* h   = (const float*)d_in[0];
    const float* e   = (const float*)d_in[1];
    const int*   src = (const int*)d_in[2];
    const int*   dst = (const int*)d_in[3];
    const float* Aw  = (const float*)d_in[4];
    const float* Ab  = (const float*)d_in[5];
    const float* Bw  = (const float*)d_in[6];
    const float* Bb  = (const float*)d_in[7];
    const float* Cw  = (const float*)d_in[8];
    const float* Cb  = (const float*)d_in[9];
    const float* Dw  = (const float*)d_in[10];
    const float* Db  = (const float*)d_in[11];
    const float* Ewt = (const float*)d_in[12];
    const float* Eb  = (const float*)d_in[13];
    const float* gh  = (const float*)d_in[14];
    const float* bh  = (const float*)d_in[15];
    const float* ge  = (const float*)d_in[16];
    const float* be  = (const float*)d_in[17];

    const int N = in_sizes[0] / 96;
    const int E = in_sizes[2];

    float* ws       = (float*)d_ws;
    float* nodeF    = ws;                               // N*384 f32
    float* node_acc = nodeF + (size_t)N * 384;          // N*192 f32
    float* h_new    = node_acc + (size_t)N * 192;       // N*96 f32
    float* stats    = h_new + (size_t)N * 96;           // 384 f32
    float* coef     = stats + 384;                      // 384 f32
    bf16_t* wb      = (bf16_t*)(coef + 384);            // 5*9216 bf16
    bf16_t* wpack   = wb + 5 * 9216;                    // 9216 bf16 (packed C_w)
    bf16_t* e_new_bf = wpack + 9216;                    // E*96 bf16 (optional)

    const size_t base_bytes = (size_t)((char*)e_new_bf - (char*)d_ws);
    const bool store_en = (ws_size >= base_bytes + (size_t)E * 96 * 2);

    // sort scratch overlapped into dead regions:
    int* cnt    = (int*)node_acc;          // N ints (before node_acc memset)
    int* rowptr = cnt + N;                 // N ints (consumed by scatter as cursor)
    int* perm   = (int*)h_new;             // E ints (dead once h_new_kernel runs)

    hipMemsetAsync(cnt, 0, (size_t)N * sizeof(int), stream);
    conv_w_kernel<<<dim3(180), dim3(256), 0, stream>>>(Aw, Bw, Cw, Dw, Ewt, wb);
    pack_cw_kernel<<<dim3(5), dim3(256), 0, stream>>>(Cw, wpack);
    node_gemm_kernel<<<dim3((N + 63) / 64, 4), dim3(256), 0, stream>>>(
        h, wb, Ab, Bb, Db, Eb, Cb, nodeF, N);
    hist_kernel<<<dim3((E + 255) / 256), dim3(256), 0, stream>>>(dst, cnt, E);
    scan_kernel<<<dim3(1), dim3(1024), 0, stream>>>(cnt, rowptr, N);
    scatter_kernel<<<dim3((E + 255) / 256), dim3(256), 0, stream>>>(dst, rowptr, perm, E);

    hipMemsetAsync(node_acc, 0, (size_t)N * 192 * sizeof(float), stream);
    hipMemsetAsync(stats, 0, 384 * sizeof(float), stream);

    if (store_en) {
        edge_agg_kernel<1><<<dim3((E + 63) / 64), dim3(256), 0, stream>>>(
            e, src, dst, perm, wpack, nodeF, node_acc, stats, e_new_bf, E);
    } else {
        edge_agg_kernel<0><<<dim3((E + 63) / 64), dim3(256), 0, stream>>>(
            e, src, dst, perm, wpack, nodeF, node_acc, stats, nullptr, E);
    }
    h_new_kernel<<<dim3((N + 31) / 32), dim3(192), 0, stream>>>(nodeF, node_acc, h_new, stats, N);
    finalize_stats_kernel<<<dim3(1), dim3(192), 0, stream>>>(stats, coef, gh, bh, ge, be, N, E);
    h_out_kernel<<<dim3((N * 24 + 255) / 256), dim3(256), 0, stream>>>(h, h_new, coef, (float*)d_out, N);

    if (store_en) {
        long long total4 = (long long)E * 24;
        edge_out_fast_kernel<<<dim3((unsigned)((total4 + 255) / 256)), dim3(256), 0, stream>>>(
            e, e_new_bf, coef, (float*)d_out + (size_t)N * 96, total4);
    } else {
        edge_out_kernel<<<dim3((E + 63) / 64), dim3(256), 0, stream>>>(
            e, src, dst, wb, nodeF, coef, (float*)d_out + (size_t)N * 96, E);
    }
}